// Round 10
// baseline (360.225 us; speedup 1.0000x reference)
//
#include <hip/hip_runtime.h>
#include <math.h>

#define N_OCT  16
#define NS     32768
#define TPB    256
#define NSPLIT 4                  // chunks per row
#define CHUNK  (NS / NSPLIT)      // 8192 samples per chunk
#define SPT    (CHUNK / TPB)      // 32 samples per thread
#define N_BE   512                // B*E = 8*64
#define NBLK   (N_BE * NSPLIT)    // 2048 blocks

typedef float v2f __attribute__((ext_vector_type(2)));
typedef _Float16 h4 __attribute__((ext_vector_type(4)));

static __device__ __forceinline__ v2f fma2(v2f a, v2f b, v2f c) {
    return __builtin_elementwise_fma(a, b, c);
}

// ws layout: [0, 32MiB) fp16 stage[N_BE][NS]; [+8KiB) float chunk_max[2048];
// [+2KiB) int done[512]. stage+max written before use every launch; done
// zeroed by the init dispatch (ws is POISONED 0xAA before every timed call).
#define WS_STAGE(ws) ((_Float16*)(ws))
#define WS_MAX(ws)   ((float*)((char*)(ws) + (size_t)N_BE * NS * 2))
#define WS_DONE(ws)  ((int*)((char*)(ws) + (size_t)N_BE * NS * 2 + 8192))

// R9 (resubmitted R10: container infra failure, no data). Evidence ledger:
// R8 single-kernel (full-row LDS stage) == R0 baseline == 36.5us regardless
// of 2x issue cuts. Decomposition: worst-CU VALU issue ~12us (v2f ops
// scalarize: R2's VALUBusy 63% x 46.2us = 29us real issue = 2x the packed
// model); the other ~24us is (a) the post-barrier 64MiB store phase that
// CANNOT overlap compute at 2 phase-locked LDS-capped blocks/CU, (b)
// 1-block/row imbalance (63% of CUs draw an NP=8 row). Any full-row-LDS
// design is pinned at 2 blocks/CU -> structural fix = chunked blocks + a
// no-spin cross-block finalizer:
//   - 2048 blocks x 256thr (4 chunks/row), ~5 blocks/CU (no big LDS) ->
//     balanced (8 draws/CU) and de-phased (stores overlap computes).
//   - chunk-block: one pass, stage unnorm fp16 -> global ws, chunk max ->
//     ws, __threadfence(), atomicAdd(done[row],1). LAST arrival (old==3)
//     fences and normalizes the whole row from the fp16 stage. No waiting
//     anywhere -> deadlock-free; early rows' finalize overlaps later rows'
//     compute (the overlap R7's two-dispatch version lacked).
//   - init dispatch zeroes done[512] (poison-proof).
// Numerics (all R7-proven, absmax at the 2^-6 reference floor): Q32 integer
// fixed-point seeds (compiler-proof; fp32-twoprod was destroyed by FP
// reassociation in R6), double-float c2 (freq err 2^-48), fp16 staging,
// dead-octave suffix skip (f0s non-decreasing in octave; dead amp=0 exact).

static __device__ __forceinline__ void make_consts(
    int be, int t,
    const float* __restrict__ f0_in, const float* __restrict__ dc_in,
    const float* __restrict__ fs_in,
    unsigned int* __restrict__ sRQ,
    float* __restrict__ sCH, float* __restrict__ sCL,
    float* __restrict__ sAMP, int* __restrict__ sLive)
{
    if (t < N_OCT) {
        const int o = t;
        const float f0a = fabsf(f0_in[be]);
        const float dc  = dc_in[be];
        const float fs  = fs_in[be];

        const float MINF = (float)(20.0 / 11025.0);
        const float FRNG = (float)(3000.0 / 11025.0 - 20.0 / 11025.0);

        // double sigmoid (reference applies sigmoid twice), decay ladder
        const float s1    = 1.0f / (1.0f + __expf(-dc));
        const float dv    = 1.0f / (1.0f + __expf(-s1));
        const float decay = 0.01f + dv * 0.9801f;          // (1-0.01)*0.99
        const float logd  = __logf(decay + 1e-12f);
        const float f0r   = (MINF + f0a * FRNG) * 3.14159274101257324f;

        // sequential float cumsum, bit-matching the reference's jnp.cumsum
        float cl = 0.f, cf = 0.f;
        for (int i = 0; i <= o; ++i) { cl += logd; cf += fs; }
        float ed  = __expf(cl);                            // decay^(o+1)
        float f0s = f0r * cf;                              // rad/sample
        float a   = ed;
        const bool live = (f0s < 1.0f);                    // nyquist cutoff
        if (!live) { a = 0.0f; f0s = 0.0f; }

        unsigned long long lm = __ballot(live);
        if (o == 0) *sLive = __popcll(lm);

        const double inv2pi = 0.15915494309189535;
        const double r = (double)f0s * inv2pi;             // revolutions/sample
        // Q32 fixed-point frequency (r < 0.16); fp64 only in this 16-lane
        // prologue.
        const unsigned int rq = (unsigned int)llrint(r * 4294967296.0);

        // c2 = 2*cos(TPB*theta) as double-float pair (single-float c2 is
        // ill-conditioned when TPB*theta mod 2pi ~ 0/pi)
        double drev = r * (double)TPB;
        drev -= floor(drev);
        double c2d = 2.0 * cos(drev * 6.283185307179586);
        float  ch  = (float)c2d;

        sRQ[o]  = rq;
        sCH[o]  = ch;
        sCL[o]  = (float)(c2d - (double)ch);
        sAMP[o] = a;
    }
}

// phase in revolutions [0,1): exact modular Q32 (low 32 bits of n*rq);
// signed n wraps correctly in two's complement. v_sin_f32 takes revolutions.
static __device__ __forceinline__ float q32_phase(int n, unsigned int rq)
{
    const unsigned int frac = (unsigned int)n * rq;
    return (float)frac * 2.3283064365386963e-10f;      // * 2^-32
}

// one recurrence pass over the chunk: stage fp16 to global ws, return lane
// max. Unroll-by-2 role swap (A: next->xp, B: next->xc): no rotation movs.
template<int NP>
static __device__ __forceinline__ float body_stage(
    int base, int t,
    const unsigned int* __restrict__ sRQ,
    const float* __restrict__ sCH, const float* __restrict__ sCL,
    const float* __restrict__ sAMP,
    _Float16* __restrict__ stage)            // global, chunk-based
{
    v2f xp[NP], xc[NP], c2h[NP], c2l[NP];

    const int n1 = base + t + 1;
    const int n0 = base + t + 1 - TPB;
    #pragma unroll
    for (int o = 0; o < 2 * NP; ++o) {
        const unsigned int rq = sRQ[o];
        const float a = sAMP[o];             // 0 for dead octaves
        float xcur  = a * __builtin_amdgcn_sinf(q32_phase(n1, rq));
        float xprev = a * __builtin_amdgcn_sinf(q32_phase(n0, rq));
        const int j = o >> 1;
        if ((o & 1) == 0) {
            xc[j].x = xcur;    xp[j].x = xprev;
            c2h[j].x = sCH[o]; c2l[j].x = sCL[o];
        } else {
            xc[j].y = xcur;    xp[j].y = xprev;
            c2h[j].y = sCH[o]; c2l[j].y = sCL[o];
        }
    }

    float lmax = 0.0f;
    #pragma unroll 2
    for (int k = 0; k < SPT; k += 2) {
        v2f accA = (v2f)(0.0f);
        #pragma unroll
        for (int j = 0; j < NP; ++j) {
            accA += xc[j];
            xp[j] = fma2(c2h[j], xc[j], fma2(c2l[j], xc[j], -xp[j]));
        }
        v2f accB = (v2f)(0.0f);
        #pragma unroll
        for (int j = 0; j < NP; ++j) {
            accB += xp[j];
            xc[j] = fma2(c2h[j], xp[j], fma2(c2l[j], xp[j], -xc[j]));
        }
        const float a = accA.x + accA.y;
        const float b = accB.x + accB.y;
        stage[k * TPB + t]       = (_Float16)a;        // 2B/lane coalesced
        stage[(k + 1) * TPB + t] = (_Float16)b;
        lmax = fmaxf(lmax, fmaxf(fabsf(a), fabsf(b)));
    }
    return lmax;
}

__global__ __launch_bounds__(512)
void f0res_init(void* __restrict__ ws)
{
    WS_DONE(ws)[threadIdx.x] = 0;                      // 512 row counters
}

__global__ __launch_bounds__(TPB)
void f0res_main(const float* __restrict__ f0_in,
                const float* __restrict__ dc_in,
                const float* __restrict__ fs_in,
                void* __restrict__ ws,
                float* __restrict__ out)
{
    __shared__ unsigned int sRQ[N_OCT];
    __shared__ float sCH[N_OCT], sCL[N_OCT], sAMP[N_OCT];
    __shared__ float wmax[TPB / 64];
    __shared__ int   sLive, sLast;

    const int bid = blockIdx.x;
    const int be  = bid >> 2;                          // row
    const int q   = bid & 3;                           // chunk
    const int t   = threadIdx.x;
    const int base = q * CHUNK;

    make_consts(be, t, f0_in, dc_in, fs_in, sRQ, sCH, sCL, sAMP, &sLive);
    __syncthreads();

    const int L = sLive;
    _Float16* __restrict__ stage = WS_STAGE(ws) + (size_t)be * NS + base;

    float lmax = 0.0f;
    if (L == 0) {
        #pragma unroll
        for (int k = 0; k < SPT; ++k) stage[k * TPB + t] = (_Float16)0.0f;
    } else if (L <= 4) {
        lmax = body_stage<2>(base, t, sRQ, sCH, sCL, sAMP, stage);
    } else if (L <= 8) {
        lmax = body_stage<4>(base, t, sRQ, sCH, sCL, sAMP, stage);
    } else {
        lmax = body_stage<8>(base, t, sRQ, sCH, sCL, sAMP, stage);
    }

    // chunk max: wave shuffle then tiny LDS
    #pragma unroll
    for (int off = 32; off > 0; off >>= 1)
        lmax = fmaxf(lmax, __shfl_down(lmax, off, 64));
    if ((t & 63) == 0) wmax[t >> 6] = lmax;
    __syncthreads();

    // publish chunk results, then last-arrival election (no spin: every
    // block proceeds immediately; only the 4th arrival takes the tail).
    if (t == 0) {
        float bmax = wmax[0];
        #pragma unroll
        for (int w = 1; w < TPB / 64; ++w) bmax = fmaxf(bmax, wmax[w]);
        WS_MAX(ws)[bid] = bmax;
        __threadfence();                               // release stage+max
        sLast = (atomicAdd(&WS_DONE(ws)[be], 1) == NSPLIT - 1);
    }
    __syncthreads();
    if (!sLast) return;                                // not last: done

    // ---- finalizer: this block normalizes the WHOLE row ----
    __threadfence();                                   // acquire others' writes

    const float* mx = WS_MAX(ws) + (be << 2);
    const float bmax = fmaxf(fmaxf(mx[0], mx[1]), fmaxf(mx[2], mx[3]));
    const float norm = 1.0f / (bmax + 1e-8f);

    const h4* __restrict__ src = (const h4*)(WS_STAGE(ws) + (size_t)be * NS);
    float4* __restrict__ dst = (float4*)(out + (size_t)be * NS);
    #pragma unroll 4
    for (int i = 0; i < NS / 4 / TPB; ++i) {           // 32 iters
        const int idx = i * TPB + t;                   // h4/float4 index
        h4 v = src[idx];                               // 8B/lane coalesced
        float4 o;
        o.x = (float)v.x * norm; o.y = (float)v.y * norm;
        o.z = (float)v.z * norm; o.w = (float)v.w * norm;
        dst[idx] = o;                                  // 16B/lane coalesced
    }
}

extern "C" void kernel_launch(void* const* d_in, const int* in_sizes, int n_in,
                              void* d_out, int out_size, void* d_ws, size_t ws_size,
                              hipStream_t stream) {
    const float* f0 = (const float*)d_in[0];
    const float* dc = (const float*)d_in[1];
    const float* fs = (const float*)d_in[3];   // d_in[2] is "unused"
    float* out = (float*)d_out;

    hipLaunchKernelGGL(f0res_init, dim3(1), dim3(512), 0, stream, d_ws);
    hipLaunchKernelGGL(f0res_main, dim3(NBLK), dim3(TPB), 0, stream,
                       f0, dc, fs, d_ws, out);
}